// Round 9
// baseline (162.597 us; speedup 1.0000x reference)
//
#include <hip/hip_runtime.h>

#define FH 50
#define FW 75
#define FC 512
#define NPOOL 7
#define NXCD 8
#define NSAMP 14   // samples per axis (CROP)

typedef float f32x4 __attribute__((ext_vector_type(4)));
typedef int   i32x4 __attribute__((ext_vector_type(4)));

// ---------------- setup: per-(roi, sample-row/col) separable tables ---------
// rowtab[n*14+j] = { off_y0 (elems), off_y1, (1-wy)*my, wy*my }
// coltab[n*14+j] = { off_x0 (elems), off_x1, (1-wx)*mx, wx*mx }
__global__ __launch_bounds__(256) void roi_setup_kernel(
    const float* __restrict__ rois,
    const int*   __restrict__ img_size,
    i32x4* __restrict__ tab,      // rowtab at [0, N*14), coltab at [N*14, 2*N*14)
    int N)
{
    const int idx = blockIdx.x * 256 + threadIdx.x;
    const int total = N * NSAMP;
    if (idx >= 2 * total) return;

    const bool is_col = idx >= total;
    const int  e = is_col ? idx - total : idx;
    const int  n = e / NSAMP;
    const int  j = e % NSAMP;

    if (!is_col) {
        const float img_h = (float)(img_size[0] - 1);
        const float ry1 = rois[n * 4 + 1];
        const float ry2 = rois[n * 4 + 3];
        const float fh = (float)(FH - 1);
        const float stepy = (ry2 - ry1) / img_h * fh * (1.0f / 13.0f);
        const float basey = ry1 / img_h * fh;
        const float ys = basey + (float)j * stepy;
        const float my = ((ys >= 0.0f) & (ys <= fh)) ? 1.0f : 0.0f;
        const float y0f = floorf(ys);
        const float wy = ys - y0f;
        int y0 = min(max((int)y0f, 0), FH - 1);
        int y1 = min(y0 + 1, FH - 1);
        i32x4 v;
        v.x = y0 * (FW * FC);
        v.y = y1 * (FW * FC);
        v.z = __float_as_int((1.0f - wy) * my);
        v.w = __float_as_int(wy * my);
        tab[e] = v;
    } else {
        const float img_w = (float)(img_size[1] - 1);
        const float rx1 = rois[n * 4 + 0];
        const float rx2 = rois[n * 4 + 2];
        const float fw = (float)(FW - 1);
        const float stepx = (rx2 - rx1) / img_w * fw * (1.0f / 13.0f);
        const float basex = rx1 / img_w * fw;
        const float xs = basex + (float)j * stepx;
        const float mx = ((xs >= 0.0f) & (xs <= fw)) ? 1.0f : 0.0f;
        const float x0f = floorf(xs);
        const float wx = xs - x0f;
        int x0 = min(max((int)x0f, 0), FW - 1);
        int x1 = min(x0 + 1, FW - 1);
        i32x4 v;
        v.x = x0 * FC;
        v.y = x1 * FC;
        v.z = __float_as_int((1.0f - wx) * mx);
        v.w = __float_as_int(wx * mx);
        tab[total + e] = v;
    }
}

// ---------------- main: table-driven gather + weighted max-pool -------------
__global__ __launch_bounds__(128) void roi_pool_kernel(
    const float* __restrict__ fmap,
    const i32x4* __restrict__ tab,   // rowtab | coltab
    float* __restrict__ out,
    int N)
{
    // bijective XCD-chunked swizzle: one ROI's 49 blocks -> one XCD
    const int nwg = gridDim.x;
    const int q = nwg / NXCD, r = nwg % NXCD;
    const int xcd = blockIdx.x % NXCD, local = blockIdx.x / NXCD;
    const int w = (xcd < r ? xcd * (q + 1) : r * (q + 1) + (xcd - r) * q) + local;

    const int n  = w / (NPOOL * NPOOL);
    const int p  = w % (NPOOL * NPOOL);
    const int py = p / NPOOL;
    const int px = p % NPOOL;
    if (n >= N) return;

    // uniform (readfirstlane'd) indices -> s_load of the 4 table entries
    const int ri = __builtin_amdgcn_readfirstlane(n * NSAMP + 2 * py);
    const int ci = __builtin_amdgcn_readfirstlane(N * NSAMP + n * NSAMP + 2 * px);
    const i32x4 R0 = tab[ri];
    const i32x4 R1 = tab[ri + 1];
    const i32x4 C0 = tab[ci];
    const i32x4 C1 = tab[ci + 1];

    const float r0a = __int_as_float(R0.z), r0b = __int_as_float(R0.w);
    const float r1a = __int_as_float(R1.z), r1b = __int_as_float(R1.w);
    const float c0a = __int_as_float(C0.z), c0b = __int_as_float(C0.w);
    const float c1a = __int_as_float(C1.z), c1b = __int_as_float(C1.w);

    const int c4 = threadIdx.x * 4;    // 128 threads * 4 ch = 512
    const float* fm = fmap + c4;

    // ---- 16 corner loads (uniform offset sums + per-thread channel) ----
    const f32x4 s00a = *(const f32x4*)(fm + R0.x + C0.x);  // sample(r0,c0) tl
    const f32x4 s00b = *(const f32x4*)(fm + R0.x + C0.y);  //               tr
    const f32x4 s00c = *(const f32x4*)(fm + R0.y + C0.x);  //               bl
    const f32x4 s00d = *(const f32x4*)(fm + R0.y + C0.y);  //               br
    const f32x4 s01a = *(const f32x4*)(fm + R0.x + C1.x);
    const f32x4 s01b = *(const f32x4*)(fm + R0.x + C1.y);
    const f32x4 s01c = *(const f32x4*)(fm + R0.y + C1.x);
    const f32x4 s01d = *(const f32x4*)(fm + R0.y + C1.y);
    const f32x4 s10a = *(const f32x4*)(fm + R1.x + C0.x);
    const f32x4 s10b = *(const f32x4*)(fm + R1.x + C0.y);
    const f32x4 s10c = *(const f32x4*)(fm + R1.y + C0.x);
    const f32x4 s10d = *(const f32x4*)(fm + R1.y + C0.y);
    const f32x4 s11a = *(const f32x4*)(fm + R1.x + C1.x);
    const f32x4 s11b = *(const f32x4*)(fm + R1.x + C1.y);
    const f32x4 s11c = *(const f32x4*)(fm + R1.y + C1.x);
    const f32x4 s11d = *(const f32x4*)(fm + R1.y + C1.y);

    // ---- weights: outer products of row/col factors ----
    const f32x4 v00 = (r0a*c0a)*s00a + (r0a*c0b)*s00b + (r0b*c0a)*s00c + (r0b*c0b)*s00d;
    const f32x4 v01 = (r0a*c1a)*s01a + (r0a*c1b)*s01b + (r0b*c1a)*s01c + (r0b*c1b)*s01d;
    const f32x4 v10 = (r1a*c0a)*s10a + (r1a*c0b)*s10b + (r1b*c0a)*s10c + (r1b*c0b)*s10d;
    const f32x4 v11 = (r1a*c1a)*s11a + (r1a*c1b)*s11b + (r1b*c1a)*s11c + (r1b*c1b)*s11d;

    f32x4 m;
    m.x = fmaxf(fmaxf(fmaxf(v00.x, v01.x), v10.x), v11.x);
    m.y = fmaxf(fmaxf(fmaxf(v00.y, v01.y), v10.y), v11.y);
    m.z = fmaxf(fmaxf(fmaxf(v00.z, v01.z), v10.z), v11.z);
    m.w = fmaxf(fmaxf(fmaxf(v00.w, v01.w), v10.w), v11.w);

    f32x4* dst = (f32x4*)(out + (((long)n * NPOOL + py) * NPOOL + px) * FC + c4);
    __builtin_nontemporal_store(m, dst);
}

extern "C" void kernel_launch(void* const* d_in, const int* in_sizes, int n_in,
                              void* d_out, int out_size, void* d_ws, size_t ws_size,
                              hipStream_t stream) {
    const float* fmap     = (const float*)d_in[0];
    const float* rois     = (const float*)d_in[1];
    const int*   img_size = (const int*)d_in[2];
    float* out = (float*)d_out;

    const int N = in_sizes[1] / 4;       // rois is (N,4)
    i32x4* tab = (i32x4*)d_ws;           // 2*N*14*16 B = 448 KB

    const int setup_threads = 2 * N * NSAMP;
    roi_setup_kernel<<<(setup_threads + 255) / 256, 256, 0, stream>>>(
        rois, img_size, tab, N);

    const int blocks = N * NPOOL * NPOOL;
    roi_pool_kernel<<<blocks, 128, 0, stream>>>(fmap, tab, out, N);
}